// Round 12
// baseline (605.626 us; speedup 1.0000x reference)
//
#include <hip/hip_runtime.h>
#include <math.h>

#define NN 100000
#define CC 64
#define EPSF 1e-8f
#define LOG_C 4.1588830833596715f
#define SCAN_BS 1024
#define NSB ((NN + SCAN_BS - 1) / SCAN_BS)
#define NREG ((NN + 1023) >> 10)     // 98 regions of 1024 rows
#define RBLK 256                     // producer blocks for the counting sort

typedef unsigned short ushortT;
typedef unsigned int uintT;
typedef unsigned int uv2 __attribute__((ext_vector_type(2)));
typedef unsigned int uv4 __attribute__((ext_vector_type(4)));
typedef float fv4 __attribute__((ext_vector_type(4)));

__device__ __forceinline__ float waveSum(float v) {
#pragma unroll
    for (int off = 32; off; off >>= 1) v += __shfl_xor(v, off);
    return v;
}
// reduce across the 8 channel-lanes (bits 0..2)
__device__ __forceinline__ float redCSum(float v) {
    v += __shfl_xor(v, 1); v += __shfl_xor(v, 2); v += __shfl_xor(v, 4);
    return v;
}
__device__ __forceinline__ float redCMax(float v) {
    v = fmaxf(v, __shfl_xor(v, 1)); v = fmaxf(v, __shfl_xor(v, 2)); v = fmaxf(v, __shfl_xor(v, 4));
    return v;
}
// reduce across the 8 edge-groups (bits 3..5)
__device__ __forceinline__ float redGSum(float v) {
    v += __shfl_xor(v, 8); v += __shfl_xor(v, 16); v += __shfl_xor(v, 32);
    return v;
}
__device__ __forceinline__ float clip01(float v) { return fminf(fmaxf(v, 0.f), 1.f); }
__device__ __forceinline__ float sigmoidf(float x) { return 1.f / (1.f + expf(-x)); }

__device__ __forceinline__ void unpack8u(uintT a, uintT b, uintT cc, uintT d, float* x) {
    x[0] = __uint_as_float(a << 16); x[1] = __uint_as_float(a & 0xFFFF0000u);
    x[2] = __uint_as_float(b << 16); x[3] = __uint_as_float(b & 0xFFFF0000u);
    x[4] = __uint_as_float(cc << 16); x[5] = __uint_as_float(cc & 0xFFFF0000u);
    x[6] = __uint_as_float(d << 16); x[7] = __uint_as_float(d & 0xFFFF0000u);
}
__device__ __forceinline__ uintT f2bf(float f) {  // RNE round to bf16 (low 16 bits)
    uintT u = __float_as_uint(f);
    return (u + 0x7FFFu + ((u >> 16) & 1u)) >> 16;
}

// ---------------- row-wise prologue ----------------

__global__ void k_seed(const float* __restrict__ logits, const float* __restrict__ sf,
                       float* __restrict__ seedF, ushortT* __restrict__ seedH,
                       float* __restrict__ mass, float* __restrict__ cert,
                       float* __restrict__ scal) {
    int lane = threadIdx.x & 63;
    int wid = threadIdx.x >> 6;
    float accm = 0.f, accc = 0.f;
    for (int row = blockIdx.x * 4 + wid; row < NN; row += gridDim.x * 4) {
        float l = __builtin_nontemporal_load(logits + row * CC + lane);
        float s = fmaxf(l, 0.f);
        __builtin_nontemporal_store(s, seedF + row * CC + lane);
        seedH[row * CC + lane] = (ushortT)f2bf(s);
        float m = waveSum(s);
        float nrm = s / (m + EPSF);
        float ent = waveSum(-nrm * logf(nrm + EPSF));
        if (lane == 0) {
            mass[row] = m;
            cert[row] = 1.f - ent / LOG_C;
            accm += m;
            accc += sf[row * 2 + 1];
        }
    }
    __shared__ float sm[8];
    if (lane == 0) { sm[wid] = accm; sm[4 + wid] = accc; }
    __syncthreads();
    if (threadIdx.x == 0) {
        atomicAdd(&scal[0], sm[0] + sm[1] + sm[2] + sm[3]);
        atomicAdd(&scal[1], sm[4] + sm[5] + sm[6] + sm[7]);
    }
}

__global__ void k_conf(const float* __restrict__ seedF, const float* __restrict__ mass,
                       const float* __restrict__ cert, float* __restrict__ conf,
                       float* __restrict__ sg, float* __restrict__ scal,
                       float* __restrict__ gp) {
    int lane = threadIdx.x & 63;
    int wid = threadIdx.x >> 6;
    float msc = fmaxf(scal[0] * (1.f / NN), EPSF);
    float accgp = 0.f, accconf = 0.f;
    for (int row = blockIdx.x * 4 + wid; row < NN; row += gridDim.x * 4) {
        float m = mass[row], ct = cert[row];
        float cf = clip01(0.5f * ct + 0.5f * tanhf(m / msc));
        accgp += cf * __builtin_nontemporal_load(seedF + row * CC + lane);
        if (lane == 0) {
            conf[row] = cf;
            sg[row] = sigmoidf(8.f * (cf - 0.55f));
            accconf += cf;
        }
    }
    __shared__ float sgp[256];
    __shared__ float scf[4];
    sgp[threadIdx.x] = accgp;
    if (lane == 0) scf[wid] = accconf;
    __syncthreads();
    if (threadIdx.x < 64)
        atomicAdd(&gp[lane], sgp[lane] + sgp[64 + lane] + sgp[128 + lane] + sgp[192 + lane]);
    if (threadIdx.x == 0) atomicAdd(&scal[2], scf[0] + scf[1] + scf[2] + scf[3]);
}

__global__ void k_finalize(float* __restrict__ scal, float* __restrict__ gp) {
    float sc = fmaxf(scal[2], EPSF);
    gp[threadIdx.x] = gp[threadIdx.x] / sc;
    if (threadIdx.x == 0) {
        scal[3] = fminf(fmaxf(1.f - scal[1] * (1.f / NN), 0.2f), 1.f);
    }
}

// ---------------- CSR build ----------------

// Fused: per-row histogram (global atomics) + per-(block,region) counts (LDS).
__global__ __launch_bounds__(256) void k_count(const int* __restrict__ dst,
                                               int* __restrict__ count,
                                               int* __restrict__ cnts, int E) {
    __shared__ int h[NREG];
    for (int i = threadIdx.x; i < NREG; i += 256) h[i] = 0;
    __syncthreads();
    int per = (E + RBLK - 1) / RBLK;
    int b0 = blockIdx.x * per;
    int b1 = min(b0 + per, E);
    for (int e = b0 + threadIdx.x; e < b1; e += 256) {
        int d = __builtin_nontemporal_load(dst + e);
        atomicAdd(&count[d], 1);
        atomicAdd(&h[d >> 10], 1);
    }
    __syncthreads();
    for (int r = threadIdx.x; r < NREG; r += 256)
        cnts[r * RBLK + blockIdx.x] = h[r];
}

__global__ void k_bsum(const int* __restrict__ count, int* __restrict__ bsum) {
    int b = blockIdx.x, t = threadIdx.x;
    int base = b * SCAN_BS + t * 4;
    int s = 0;
#pragma unroll
    for (int k = 0; k < 4; ++k) {
        int i = base + k;
        if (i < NN) s += count[i];
    }
#pragma unroll
    for (int off = 32; off; off >>= 1) s += __shfl_xor(s, off);
    __shared__ int red[4];
    if ((t & 63) == 0) red[t >> 6] = s;
    __syncthreads();
    if (t == 0) bsum[b] = red[0] + red[1] + red[2] + red[3];
}

__global__ void k_boff(const int* __restrict__ bsum, int* __restrict__ boff,
                       int* __restrict__ row_start) {
    int acc = 0;
    for (int i = 0; i < NSB; ++i) { boff[i] = acc; acc += bsum[i]; }
    row_start[NN] = acc;  // == E
}

__global__ void k_scanwrite(const int* __restrict__ count, const int* __restrict__ boff,
                            int* __restrict__ row_start, int* __restrict__ cursor) {
    int b = blockIdx.x, t = threadIdx.x, lane = t & 63, wid = t >> 6;
    int base = b * SCAN_BS + t * 4;
    int c0 = 0, c1 = 0, c2 = 0, c3 = 0;
    if (base < NN) c0 = count[base];
    if (base + 1 < NN) c1 = count[base + 1];
    if (base + 2 < NN) c2 = count[base + 2];
    if (base + 3 < NN) c3 = count[base + 3];
    int s = c0 + c1 + c2 + c3;
    int incl = s;
#pragma unroll
    for (int off = 1; off < 64; off <<= 1) {
        int o = __shfl_up(incl, off);
        if (lane >= off) incl += o;
    }
    __shared__ int wsum[4];
    if (lane == 63) wsum[wid] = incl;
    __syncthreads();
    int woff = 0;
    for (int i = 0; i < wid; ++i) woff += wsum[i];
    int excl = boff[b] + woff + incl - s;
    if (base < NN) { row_start[base] = excl; cursor[base] = excl; excl += c0; }
    if (base + 1 < NN) { row_start[base + 1] = excl; cursor[base + 1] = excl; excl += c1; }
    if (base + 2 < NN) { row_start[base + 2] = excl; cursor[base + 2] = excl; excl += c2; }
    if (base + 3 < NN) { row_start[base + 3] = excl; cursor[base + 3] = excl; excl += c3; }
}

// Phase B of counting sort: exclusive scan of cnts (r-major, b-minor).
__global__ __launch_bounds__(1024) void k_rscan(const int* __restrict__ cnts,
                                                int* __restrict__ offs) {
    const int TOT = NREG * RBLK;          // 25088
    const int PER = (TOT + 1023) / 1024;  // 25
    int t = threadIdx.x, lane = t & 63, wid = t >> 6;
    int base = t * PER;
    int loc[PER];
    int s = 0;
#pragma unroll
    for (int k = 0; k < PER; ++k) {
        int i = base + k;
        int v = (i < TOT) ? cnts[i] : 0;
        loc[k] = s;
        s += v;
    }
    int incl = s;
#pragma unroll
    for (int off = 1; off < 64; off <<= 1) {
        int o = __shfl_up(incl, off);
        if (lane >= off) incl += o;
    }
    __shared__ int wsum[16];
    if (lane == 63) wsum[wid] = incl;
    __syncthreads();
    int woff = 0;
    for (int i = 0; i < wid; ++i) woff += wsum[i];
    int excl = woff + incl - s;
#pragma unroll
    for (int k = 0; k < PER; ++k) {
        int i = base + k;
        if (i < TOT) offs[i] = excl + loc[k];
    }
}

// Phase C: place records at block-private frontiers (LDS cursors, dense writes).
__global__ __launch_bounds__(256) void k_rbin(const int* __restrict__ src,
                                              const int* __restrict__ dst,
                                              const float* __restrict__ w,
                                              const int* __restrict__ offs,
                                              int2* __restrict__ tmp_pk, int E) {
    __shared__ int cur[NREG];
    for (int r = threadIdx.x; r < NREG; r += 256)
        cur[r] = offs[r * RBLK + blockIdx.x];
    __syncthreads();
    int per = (E + RBLK - 1) / RBLK;
    int b0 = blockIdx.x * per;
    int b1 = min(b0 + per, E);
    for (int e = b0 + threadIdx.x; e < b1; e += 256) {
        int d = __builtin_nontemporal_load(dst + e);
        int sv = __builtin_nontemporal_load(src + e);
        float wv = __builtin_nontemporal_load(w + e);
        int r = d >> 10;
        int pos = atomicAdd(&cur[r], 1);
        uv2 rec;
        rec.x = (uintT)(sv | ((d & 1023) << 17));
        rec.y = __float_as_uint(wv);
        __builtin_nontemporal_store(rec, (uv2*)(tmp_pk + pos));
    }
}

// Phase D: one block per region permutes its contiguous slice to row positions.
__global__ __launch_bounds__(256) void k_runbin(const int* __restrict__ row_start,
                                                const int2* __restrict__ tmp_pk,
                                                int2* __restrict__ edge_pk) {
    __shared__ int cur[1024];
    int r0 = blockIdx.x << 10;
    int r1 = min(r0 + 1024, NN);
    for (int i = threadIdx.x; i < r1 - r0; i += 256) cur[i] = row_start[r0 + i];
    __syncthreads();
    int s = row_start[r0], e = row_start[r1];
    for (int i = s + threadIdx.x; i < e; i += 256) {
        uv2 t = __builtin_nontemporal_load((const uv2*)(tmp_pk + i));
        int dl = (t.x >> 17) & 1023;
        int pos = atomicAdd(&cur[dl], 1);
        edge_pk[pos] = make_int2((int)(t.x & 0x1FFFF), (int)t.y);
    }
}

// Fallback (ws too small): proven direct per-row scatter.
__global__ void k_scatter(const int* __restrict__ src, const int* __restrict__ dst,
                          const float* __restrict__ w, int* __restrict__ cursor,
                          int2* __restrict__ edge_pk, int E) {
    int i = blockIdx.x * blockDim.x + threadIdx.x;
    int stride = gridDim.x * blockDim.x;
    for (; i < E; i += stride) {
        int d = dst[i];
        int pos = atomicAdd(&cursor[d], 1);
        edge_pk[pos] = make_int2(src[i], __float_as_int(w[i]));
    }
}

// ---------------- fused CSR gather (bf16) + update, one wave per row -------
// Lane layout: g = lane>>3 (edge slot 0..7), c = lane&7 (channel octet).
// Streams (edge_pk, seedF, prop/out writes) use nontemporal (nt) access so the
// 12.8 MB bf16 gather state keeps L2 residency; gathers of xH stay cached.

template <int MODE>
__global__ __launch_bounds__(256) void k_csr(
    const int2* __restrict__ edge_pk, const int* __restrict__ row_start,
    const ushortT* __restrict__ xH, const float* __restrict__ sg,
    const float* __restrict__ seedF, const float* __restrict__ sf,
    const float* __restrict__ conf, const float* __restrict__ gp,
    const float* __restrict__ scal, float* __restrict__ den,
    float* __restrict__ bq, ushortT* __restrict__ poutH,
    float* __restrict__ outF) {
    int lane = threadIdx.x & 63;
    int row = blockIdx.x * 4 + (threadIdx.x >> 6);
    if (row >= NN) return;
    int g = lane >> 3, c = lane & 7;
    int rs = row_start[row], re = row_start[row + 1];

    float acc[8], accn[8];
    float accden = 0.f;
#pragma unroll
    for (int i = 0; i < 8; ++i) { acc[i] = 0.f; accn[i] = 0.f; }

    for (int base = rs; base < re; base += 16) {
        int e0 = base + g;
        int e1 = base + 8 + g;
        uv2 pk0 = {0u, 0u}, pk1 = {0u, 0u};
        if (e0 < re) pk0 = __builtin_nontemporal_load((const uv2*)(edge_pk + e0));
        if (e1 < re) pk1 = __builtin_nontemporal_load((const uv2*)(edge_pk + e1));
        int s0 = (int)pk0.x, s1 = (int)pk1.x;
        float w0 = __uint_as_float(pk0.y);
        float w1 = __uint_as_float(pk1.y);
        const uint4 v0 = *(const uint4*)(xH + (size_t)s0 * CC + c * 8);
        const uint4 v1 = *(const uint4*)(xH + (size_t)s1 * CC + c * 8);
        float x0[8], x1[8];
        unpack8u(v0.x, v0.y, v0.z, v0.w, x0);
        unpack8u(v1.x, v1.y, v1.z, v1.w, x1);
        float wa0 = w0, wa1 = w1;
        if (MODE == 1) { wa0 = w0 * sg[s0]; wa1 = w1 * sg[s1]; }
#pragma unroll
        for (int i = 0; i < 8; ++i) acc[i] += wa0 * x0[i] + wa1 * x1[i];
        if (MODE == 0) {
            float ws0 = w0 * sg[s0];
            float ws1 = w1 * sg[s1];
#pragma unroll
            for (int i = 0; i < 8; ++i) accn[i] += ws0 * x0[i] + ws1 * x1[i];
            accden += ws0 + ws1;
        }
    }

#pragma unroll
    for (int i = 0; i < 8; ++i) acc[i] = redGSum(acc[i]);

    if (MODE == 1) {
        float dn = fmaxf(den[row], EPSF);
        float inv = 1.f / dn;
        float p[8], s[8], g8[8], f[8];
        uint4 pv = *(const uint4*)(xH + (size_t)row * CC + c * 8);
        unpack8u(pv.x, pv.y, pv.z, pv.w, p);
        fv4 sa = __builtin_nontemporal_load((const fv4*)(seedF + (size_t)row * CC + c * 8));
        fv4 sb = __builtin_nontemporal_load((const fv4*)(seedF + (size_t)row * CC + c * 8 + 4));
        s[0] = sa.x; s[1] = sa.y; s[2] = sa.z; s[3] = sa.w;
        s[4] = sb.x; s[5] = sb.y; s[6] = sb.z; s[7] = sb.w;
        const float4 ga = *(const float4*)(gp + c * 8);
        const float4 gb = *(const float4*)(gp + c * 8 + 4);
        g8[0] = ga.x; g8[1] = ga.y; g8[2] = ga.z; g8[3] = ga.w;
        g8[4] = gb.x; g8[5] = gb.y; g8[6] = gb.z; g8[7] = gb.w;
        float pf = 0.f, pp = 0.f, ff = 0.f, sfv = 0.f, ss = 0.f;
#pragma unroll
        for (int i = 0; i < 8; ++i) {
            f[i] = 0.95f * (acc[i] * inv) + 0.05f * g8[i];
            pf += p[i] * f[i]; pp += p[i] * p[i]; ff += f[i] * f[i];
            sfv += s[i] * f[i]; ss += s[i] * s[i];
        }
        pf = redCSum(pf); pp = redCSum(pp); ff = redCSum(ff);
        sfv = redCSum(sfv); ss = redCSum(ss);
        float nf = fmaxf(sqrtf(ff), 1e-8f);
        float agree = clip01((pf / (fmaxf(sqrtf(pp), 1e-8f) * nf) + 1.f) * 0.5f);
        float sagree = clip01((sfv / (fmaxf(sqrtf(ss), 1e-8f) * nf) + 1.f) * 0.5f);
        float cf = conf[row];
        float anchor = fminf(fmaxf(0.6f + 0.2f * cf, 0.f), 0.995f);
        float lowdeg = clip01(1.f - sf[row * 2 + 0]);
        float lowcl = clip01(1.f - sf[row * 2 + 1]);
        float rec = sigmoidf(8.f * (0.5f - cf));
        float sel = clip01((1.f - cf) + 0.25f * lowdeg + 0.2f * sagree + 0.2f * lowcl);
        float ug = rec * sel * agree * (1.f - anchor);
        float rsc = 0.15f * scal[3] * ug;
        if (g == 0) {
            float o[8];
#pragma unroll
            for (int i = 0; i < 8; ++i)
                o[i] = fmaxf(anchor * s[i] + (1.f - anchor) * p[i] + rsc * (f[i] - p[i]), 0.f);
            uv4 ov;
            ov.x = f2bf(o[0]) | (f2bf(o[1]) << 16);
            ov.y = f2bf(o[2]) | (f2bf(o[3]) << 16);
            ov.z = f2bf(o[4]) | (f2bf(o[5]) << 16);
            ov.w = f2bf(o[6]) | (f2bf(o[7]) << 16);
            __builtin_nontemporal_store(ov, (uv4*)(poutH + (size_t)row * CC + c * 8));
        }
        return;
    }

    // MODE 0 / MODE 2: quality epilogue. s = seed row (fp32) or prop row (bf16).
    float s[8];
    if (MODE == 0) {
        fv4 sa = __builtin_nontemporal_load((const fv4*)(seedF + (size_t)row * CC + c * 8));
        fv4 sb = __builtin_nontemporal_load((const fv4*)(seedF + (size_t)row * CC + c * 8 + 4));
        s[0] = sa.x; s[1] = sa.y; s[2] = sa.z; s[3] = sa.w;
        s[4] = sb.x; s[5] = sb.y; s[6] = sb.z; s[7] = sb.w;
    } else {
        uint4 pv = *(const uint4*)(xH + (size_t)row * CC + c * 8);
        unpack8u(pv.x, pv.y, pv.z, pv.w, s);
    }
    float dot = 0.f, ss = 0.f, cc2 = 0.f, m = 0.f;
#pragma unroll
    for (int i = 0; i < 8; ++i) {
        dot += s[i] * acc[i]; ss += s[i] * s[i]; cc2 += acc[i] * acc[i]; m += s[i];
    }
    dot = redCSum(dot); ss = redCSum(ss); cc2 = redCSum(cc2); m = redCSum(m);
    float cosv = dot / (fmaxf(sqrtf(ss), 1e-8f) * fmaxf(sqrtf(cc2), 1e-8f));
    float lq = clip01((cosv + 1.f) * 0.5f);
    float minv = 1.f / (m + EPSF);
    float lmax = -3.4e38f;
#pragma unroll
    for (int i = 0; i < 8; ++i) lmax = fmaxf(lmax, s[i] * minv);
    float m1 = redCMax(lmax);
    float cnt = 0.f, mlt = -3.4e38f;
#pragma unroll
    for (int i = 0; i < 8; ++i) {
        float p = s[i] * minv;
        cnt += (p == m1) ? 1.f : 0.f;
        mlt = fmaxf(mlt, (p < m1) ? p : -3.4e38f);
    }
    cnt = redCSum(cnt);
    mlt = redCMax(mlt);
    float m2 = (cnt >= 2.f) ? m1 : mlt;
    float q = 0.7f * lq + 0.2f * (m1 - m2) + 0.1f * sf[row * 2 + 1];

    if (MODE == 0) {
#pragma unroll
        for (int i = 0; i < 8; ++i) accn[i] = redGSum(accn[i]);
        accden = redGSum(accden);
        float dn = fmaxf(accden, EPSF);
        float inv = 1.f / dn;
        float g8[8], f[8];
        const float4 ga = *(const float4*)(gp + c * 8);
        const float4 gb = *(const float4*)(gp + c * 8 + 4);
        g8[0] = ga.x; g8[1] = ga.y; g8[2] = ga.z; g8[3] = ga.w;
        g8[4] = gb.x; g8[5] = gb.y; g8[6] = gb.z; g8[7] = gb.w;
        float sfv = 0.f, ff = 0.f;
#pragma unroll
        for (int i = 0; i < 8; ++i) {
            f[i] = 0.95f * (accn[i] * inv) + 0.05f * g8[i];
            sfv += s[i] * f[i]; ff += f[i] * f[i];
        }
        sfv = redCSum(sfv); ff = redCSum(ff);
        float nf = fmaxf(sqrtf(ff), 1e-8f);
        float sagree = clip01((sfv / (fmaxf(sqrtf(ss), 1e-8f) * nf) + 1.f) * 0.5f);
        float cf = conf[row];
        float anchor = fminf(fmaxf(0.6f + 0.2f * cf, 0.f), 0.995f);
        float lowdeg = clip01(1.f - sf[row * 2 + 0]);
        float lowcl = clip01(1.f - sf[row * 2 + 1]);
        float rec = sigmoidf(8.f * (0.5f - cf));
        float sel = clip01((1.f - cf) + 0.25f * lowdeg + 0.2f * sagree + 0.2f * lowcl);
        float ug = rec * sel * sagree * (1.f - anchor);
        float rsc = 0.15f * scal[3] * ug;
        if (g == 0) {
            float o[8];
#pragma unroll
            for (int i = 0; i < 8; ++i) o[i] = fmaxf(s[i] + rsc * (f[i] - s[i]), 0.f);
            uv4 ov;
            ov.x = f2bf(o[0]) | (f2bf(o[1]) << 16);
            ov.y = f2bf(o[2]) | (f2bf(o[3]) << 16);
            ov.z = f2bf(o[4]) | (f2bf(o[5]) << 16);
            ov.w = f2bf(o[6]) | (f2bf(o[7]) << 16);
            __builtin_nontemporal_store(ov, (uv4*)(poutH + (size_t)row * CC + c * 8));
        }
        if (lane == 0) {
            den[row] = accden;
            bq[row] = q;
        }
    } else {  // MODE 2: accept + blend -> fp32 out
        float accp = sigmoidf(12.f * (q - bq[row]));
        fv4 sa = __builtin_nontemporal_load((const fv4*)(seedF + (size_t)row * CC + c * 8));
        fv4 sb = __builtin_nontemporal_load((const fv4*)(seedF + (size_t)row * CC + c * 8 + 4));
        float sd[8] = {sa.x, sa.y, sa.z, sa.w, sb.x, sb.y, sb.z, sb.w};
        if (g == 0) {
            fv4 o1, o2;
            o1.x = accp * s[0] + (1.f - accp) * sd[0];
            o1.y = accp * s[1] + (1.f - accp) * sd[1];
            o1.z = accp * s[2] + (1.f - accp) * sd[2];
            o1.w = accp * s[3] + (1.f - accp) * sd[3];
            o2.x = accp * s[4] + (1.f - accp) * sd[4];
            o2.y = accp * s[5] + (1.f - accp) * sd[5];
            o2.z = accp * s[6] + (1.f - accp) * sd[6];
            o2.w = accp * s[7] + (1.f - accp) * sd[7];
            __builtin_nontemporal_store(o1, (fv4*)(outF + (size_t)row * CC + c * 8));
            __builtin_nontemporal_store(o2, (fv4*)(outF + (size_t)row * CC + c * 8 + 4));
        }
    }
}

// ---------------- launcher ----------------

extern "C" void kernel_launch(void* const* d_in, const int* in_sizes, int n_in,
                              void* d_out, int out_size, void* d_ws, size_t ws_size,
                              hipStream_t stream) {
    const float* logits = (const float*)d_in[0];
    const float* ew = (const float*)d_in[1];
    const float* sf = (const float*)d_in[2];
    const int* esrc = (const int*)d_in[3];
    const int* edst = (const int*)d_in[4];
    float* out = (float*)d_out;
    int E = in_sizes[1];

    float* ws = (float*)d_ws;
    float* seedF = ws;                             // N*C fp32   (25.6 MB)
    ushortT* seedH = (ushortT*)(seedF + NN * CC);  // N*C bf16   (12.8 MB)
    ushortT* propAH = seedH + NN * CC;             // N*C bf16   (12.8 MB)
    int2* edge_pk = (int2*)(propAH + NN * CC);     // E int2     (12.8 MB)
    int2* tmp_pk = edge_pk + E;                    // E int2     (12.8 MB)
    float* fb = (float*)(tmp_pk + E);
    float* massA = fb;                             // N
    float* certA = massA + NN;                     // N
    float* confA = certA + NN;                     // N
    float* sgA = confA + NN;                       // N
    float* denA = sgA + NN;                        // N
    float* bqA = denA + NN;                        // N
    float* scal = bqA + NN;                        // 16
    float* gp = scal + 16;                         // 64
    int* count = (int*)(gp + 64);                  // N
    int* cursor = count + NN;                      // N
    int* row_start = cursor + NN;                  // N+1
    int* bsum = row_start + NN + 1;                // NSB
    int* boff = bsum + NSB;                        // NSB
    int* cnts = boff + NSB;                        // NREG*RBLK
    int* offs = cnts + NREG * RBLK;                // NREG*RBLK
    ushortT* propBH = (ushortT*)d_out;             // dead before final write

    size_t need_bytes = (size_t)((char*)(offs + NREG * RBLK) - (char*)ws);
    bool sort_path = ws_size >= need_bytes;

    hipMemsetAsync(scal, 0, 16 * sizeof(float), stream);
    hipMemsetAsync(count, 0, NN * sizeof(int), stream);

    const int redBlocks = 1024;
    const int rowBlocks = (NN + 3) / 4;
    const int edgeBlocks = 1024;

    k_seed<<<redBlocks, 256, 0, stream>>>(logits, sf, seedF, seedH, massA, certA, scal);
    k_conf<<<redBlocks, 256, 0, stream>>>(seedF, massA, certA, confA, sgA, scal, gp);
    k_finalize<<<1, 64, 0, stream>>>(scal, gp);

    k_count<<<RBLK, 256, 0, stream>>>(edst, count, cnts, E);
    k_bsum<<<NSB, 256, 0, stream>>>(count, bsum);
    k_boff<<<1, 1, 0, stream>>>(bsum, boff, row_start);
    k_scanwrite<<<NSB, 256, 0, stream>>>(count, boff, row_start, cursor);

    if (sort_path) {
        k_rscan<<<1, 1024, 0, stream>>>(cnts, offs);
        k_rbin<<<RBLK, 256, 0, stream>>>(esrc, edst, ew, offs, tmp_pk, E);
        k_runbin<<<NREG, 256, 0, stream>>>(row_start, tmp_pk, edge_pk);
    } else {
        k_scatter<<<edgeBlocks, 256, 0, stream>>>(esrc, edst, ew, cursor, edge_pk, E);
    }

    // base pass: ctx(seed) quality + den + fused step-0 update -> propAH
    k_csr<0><<<rowBlocks, 256, 0, stream>>>(edge_pk, row_start, seedH, sgA, seedF, sf,
                                            confA, gp, scal, denA, bqA, propAH, nullptr);
    // steps 1,2: gather + fused update, ping-pong propAH <-> propBH(d_out)
    k_csr<1><<<rowBlocks, 256, 0, stream>>>(edge_pk, row_start, propAH, sgA, seedF, sf,
                                            confA, gp, scal, denA, bqA, propBH, nullptr);
    k_csr<1><<<rowBlocks, 256, 0, stream>>>(edge_pk, row_start, propBH, sgA, seedF, sf,
                                            confA, gp, scal, denA, bqA, propAH, nullptr);
    // final: ctx(propAH) + quality + accept + blend -> fp32 out (overwrites dead propBH)
    k_csr<2><<<rowBlocks, 256, 0, stream>>>(edge_pk, row_start, propAH, sgA, seedF, sf,
                                            confA, gp, scal, denA, bqA, nullptr, out);
}

// Round 13
// 520.285 us; speedup vs baseline: 1.1640x; 1.1640x over previous
//
#include <hip/hip_runtime.h>
#include <math.h>

#define NN 100000
#define CC 64
#define EPSF 1e-8f
#define LOG_C 4.1588830833596715f
#define SCAN_BS 1024
#define NSB ((NN + SCAN_BS - 1) / SCAN_BS)
#define NREG ((NN + 1023) >> 10)     // 98 regions of 1024 rows
#define RBLK 256                     // producer blocks for the counting sort

typedef unsigned short ushortT;
typedef unsigned int uintT;

__device__ __forceinline__ float waveSum(float v) {
#pragma unroll
    for (int off = 32; off; off >>= 1) v += __shfl_xor(v, off);
    return v;
}
// reduce across the 8 channel-lanes (bits 0..2)
__device__ __forceinline__ float redCSum(float v) {
    v += __shfl_xor(v, 1); v += __shfl_xor(v, 2); v += __shfl_xor(v, 4);
    return v;
}
__device__ __forceinline__ float redCMax(float v) {
    v = fmaxf(v, __shfl_xor(v, 1)); v = fmaxf(v, __shfl_xor(v, 2)); v = fmaxf(v, __shfl_xor(v, 4));
    return v;
}
// reduce across the 8 edge-groups (bits 3..5)
__device__ __forceinline__ float redGSum(float v) {
    v += __shfl_xor(v, 8); v += __shfl_xor(v, 16); v += __shfl_xor(v, 32);
    return v;
}
__device__ __forceinline__ float clip01(float v) { return fminf(fmaxf(v, 0.f), 1.f); }
__device__ __forceinline__ float sigmoidf(float x) { return 1.f / (1.f + expf(-x)); }

__device__ __forceinline__ void unpack8(const uint4 v, float* x) {
    x[0] = __uint_as_float(v.x << 16); x[1] = __uint_as_float(v.x & 0xFFFF0000u);
    x[2] = __uint_as_float(v.y << 16); x[3] = __uint_as_float(v.y & 0xFFFF0000u);
    x[4] = __uint_as_float(v.z << 16); x[5] = __uint_as_float(v.z & 0xFFFF0000u);
    x[6] = __uint_as_float(v.w << 16); x[7] = __uint_as_float(v.w & 0xFFFF0000u);
}
__device__ __forceinline__ uintT f2bf(float f) {  // RNE round to bf16 (low 16 bits)
    uintT u = __float_as_uint(f);
    return (u + 0x7FFFu + ((u >> 16) & 1u)) >> 16;
}
__device__ __forceinline__ uint4 pack8(const float* x) {
    uint4 o;
    o.x = f2bf(x[0]) | (f2bf(x[1]) << 16);
    o.y = f2bf(x[2]) | (f2bf(x[3]) << 16);
    o.z = f2bf(x[4]) | (f2bf(x[5]) << 16);
    o.w = f2bf(x[6]) | (f2bf(x[7]) << 16);
    return o;
}

// ---------------- row-wise prologue ----------------

__global__ void k_seed(const float* __restrict__ logits, const float* __restrict__ sf,
                       float* __restrict__ seedF, ushortT* __restrict__ seedH,
                       float* __restrict__ mass, float* __restrict__ cert,
                       float* __restrict__ scal) {
    int lane = threadIdx.x & 63;
    int wid = threadIdx.x >> 6;
    float accm = 0.f, accc = 0.f;
    for (int row = blockIdx.x * 4 + wid; row < NN; row += gridDim.x * 4) {
        float l = logits[row * CC + lane];
        float s = fmaxf(l, 0.f);
        seedF[row * CC + lane] = s;
        seedH[row * CC + lane] = (ushortT)f2bf(s);
        float m = waveSum(s);
        float nrm = s / (m + EPSF);
        float ent = waveSum(-nrm * logf(nrm + EPSF));
        if (lane == 0) {
            mass[row] = m;
            cert[row] = 1.f - ent / LOG_C;
            accm += m;
            accc += sf[row * 2 + 1];
        }
    }
    __shared__ float sm[8];
    if (lane == 0) { sm[wid] = accm; sm[4 + wid] = accc; }
    __syncthreads();
    if (threadIdx.x == 0) {
        atomicAdd(&scal[0], sm[0] + sm[1] + sm[2] + sm[3]);
        atomicAdd(&scal[1], sm[4] + sm[5] + sm[6] + sm[7]);
    }
}

__global__ void k_conf(const float* __restrict__ seedF, const float* __restrict__ mass,
                       const float* __restrict__ cert, float* __restrict__ conf,
                       float* __restrict__ sg, float* __restrict__ scal,
                       float* __restrict__ gp) {
    int lane = threadIdx.x & 63;
    int wid = threadIdx.x >> 6;
    float msc = fmaxf(scal[0] * (1.f / NN), EPSF);
    float accgp = 0.f, accconf = 0.f;
    for (int row = blockIdx.x * 4 + wid; row < NN; row += gridDim.x * 4) {
        float m = mass[row], ct = cert[row];
        float cf = clip01(0.5f * ct + 0.5f * tanhf(m / msc));
        accgp += cf * seedF[row * CC + lane];
        if (lane == 0) {
            conf[row] = cf;
            sg[row] = sigmoidf(8.f * (cf - 0.55f));
            accconf += cf;
        }
    }
    __shared__ float sgp[256];
    __shared__ float scf[4];
    sgp[threadIdx.x] = accgp;
    if (lane == 0) scf[wid] = accconf;
    __syncthreads();
    if (threadIdx.x < 64)
        atomicAdd(&gp[lane], sgp[lane] + sgp[64 + lane] + sgp[128 + lane] + sgp[192 + lane]);
    if (threadIdx.x == 0) atomicAdd(&scal[2], scf[0] + scf[1] + scf[2] + scf[3]);
}

__global__ void k_finalize(float* __restrict__ scal, float* __restrict__ gp) {
    float sc = fmaxf(scal[2], EPSF);
    gp[threadIdx.x] = gp[threadIdx.x] / sc;
    if (threadIdx.x == 0) {
        scal[3] = fminf(fmaxf(1.f - scal[1] * (1.f / NN), 0.2f), 1.f);
    }
}

// ---------------- CSR build ----------------

// Fused: per-row histogram (global atomics) + per-(block,region) counts (LDS).
__global__ __launch_bounds__(256) void k_count(const int* __restrict__ dst,
                                               int* __restrict__ count,
                                               int* __restrict__ cnts, int E) {
    __shared__ int h[NREG];
    for (int i = threadIdx.x; i < NREG; i += 256) h[i] = 0;
    __syncthreads();
    int per = (E + RBLK - 1) / RBLK;
    int b0 = blockIdx.x * per;
    int b1 = min(b0 + per, E);
    for (int e = b0 + threadIdx.x; e < b1; e += 256) {
        int d = dst[e];
        atomicAdd(&count[d], 1);
        atomicAdd(&h[d >> 10], 1);
    }
    __syncthreads();
    for (int r = threadIdx.x; r < NREG; r += 256)
        cnts[r * RBLK + blockIdx.x] = h[r];
}

__global__ void k_bsum(const int* __restrict__ count, int* __restrict__ bsum) {
    int b = blockIdx.x, t = threadIdx.x;
    int base = b * SCAN_BS + t * 4;
    int s = 0;
#pragma unroll
    for (int k = 0; k < 4; ++k) {
        int i = base + k;
        if (i < NN) s += count[i];
    }
#pragma unroll
    for (int off = 32; off; off >>= 1) s += __shfl_xor(s, off);
    __shared__ int red[4];
    if ((t & 63) == 0) red[t >> 6] = s;
    __syncthreads();
    if (t == 0) bsum[b] = red[0] + red[1] + red[2] + red[3];
}

__global__ void k_boff(const int* __restrict__ bsum, int* __restrict__ boff,
                       int* __restrict__ row_start) {
    int acc = 0;
    for (int i = 0; i < NSB; ++i) { boff[i] = acc; acc += bsum[i]; }
    row_start[NN] = acc;  // == E
}

__global__ void k_scanwrite(const int* __restrict__ count, const int* __restrict__ boff,
                            int* __restrict__ row_start, int* __restrict__ cursor) {
    int b = blockIdx.x, t = threadIdx.x, lane = t & 63, wid = t >> 6;
    int base = b * SCAN_BS + t * 4;
    int c0 = 0, c1 = 0, c2 = 0, c3 = 0;
    if (base < NN) c0 = count[base];
    if (base + 1 < NN) c1 = count[base + 1];
    if (base + 2 < NN) c2 = count[base + 2];
    if (base + 3 < NN) c3 = count[base + 3];
    int s = c0 + c1 + c2 + c3;
    int incl = s;
#pragma unroll
    for (int off = 1; off < 64; off <<= 1) {
        int o = __shfl_up(incl, off);
        if (lane >= off) incl += o;
    }
    __shared__ int wsum[4];
    if (lane == 63) wsum[wid] = incl;
    __syncthreads();
    int woff = 0;
    for (int i = 0; i < wid; ++i) woff += wsum[i];
    int excl = boff[b] + woff + incl - s;
    if (base < NN) { row_start[base] = excl; cursor[base] = excl; excl += c0; }
    if (base + 1 < NN) { row_start[base + 1] = excl; cursor[base + 1] = excl; excl += c1; }
    if (base + 2 < NN) { row_start[base + 2] = excl; cursor[base + 2] = excl; excl += c2; }
    if (base + 3 < NN) { row_start[base + 3] = excl; cursor[base + 3] = excl; excl += c3; }
}

// Phase B of counting sort: exclusive scan of cnts (r-major, b-minor).
__global__ __launch_bounds__(1024) void k_rscan(const int* __restrict__ cnts,
                                                int* __restrict__ offs) {
    const int TOT = NREG * RBLK;          // 25088
    const int PER = (TOT + 1023) / 1024;  // 25
    int t = threadIdx.x, lane = t & 63, wid = t >> 6;
    int base = t * PER;
    int loc[PER];
    int s = 0;
#pragma unroll
    for (int k = 0; k < PER; ++k) {
        int i = base + k;
        int v = (i < TOT) ? cnts[i] : 0;
        loc[k] = s;
        s += v;
    }
    int incl = s;
#pragma unroll
    for (int off = 1; off < 64; off <<= 1) {
        int o = __shfl_up(incl, off);
        if (lane >= off) incl += o;
    }
    __shared__ int wsum[16];
    if (lane == 63) wsum[wid] = incl;
    __syncthreads();
    int woff = 0;
    for (int i = 0; i < wid; ++i) woff += wsum[i];
    int excl = woff + incl - s;
#pragma unroll
    for (int k = 0; k < PER; ++k) {
        int i = base + k;
        if (i < TOT) offs[i] = excl + loc[k];
    }
}

// Phase C: place records at block-private frontiers (LDS cursors, dense writes).
__global__ __launch_bounds__(256) void k_rbin(const int* __restrict__ src,
                                              const int* __restrict__ dst,
                                              const float* __restrict__ w,
                                              const int* __restrict__ offs,
                                              int2* __restrict__ tmp_pk, int E) {
    __shared__ int cur[NREG];
    for (int r = threadIdx.x; r < NREG; r += 256)
        cur[r] = offs[r * RBLK + blockIdx.x];
    __syncthreads();
    int per = (E + RBLK - 1) / RBLK;
    int b0 = blockIdx.x * per;
    int b1 = min(b0 + per, E);
    for (int e = b0 + threadIdx.x; e < b1; e += 256) {
        int d = dst[e];
        int r = d >> 10;
        int pos = atomicAdd(&cur[r], 1);
        tmp_pk[pos] = make_int2(src[e] | ((d & 1023) << 17), __float_as_int(w[e]));
    }
}

// Phase D: one block per region permutes its contiguous slice to row positions.
__global__ __launch_bounds__(256) void k_runbin(const int* __restrict__ row_start,
                                                const int2* __restrict__ tmp_pk,
                                                int2* __restrict__ edge_pk) {
    __shared__ int cur[1024];
    int r0 = blockIdx.x << 10;
    int r1 = min(r0 + 1024, NN);
    for (int i = threadIdx.x; i < r1 - r0; i += 256) cur[i] = row_start[r0 + i];
    __syncthreads();
    int s = row_start[r0], e = row_start[r1];
    for (int i = s + threadIdx.x; i < e; i += 256) {
        int2 t = tmp_pk[i];
        int dl = (t.x >> 17) & 1023;
        int pos = atomicAdd(&cur[dl], 1);
        edge_pk[pos] = make_int2(t.x & 0x1FFFF, t.y);
    }
}

// Fallback (ws too small): proven direct per-row scatter.
__global__ void k_scatter(const int* __restrict__ src, const int* __restrict__ dst,
                          const float* __restrict__ w, int* __restrict__ cursor,
                          int2* __restrict__ edge_pk, int E) {
    int i = blockIdx.x * blockDim.x + threadIdx.x;
    int stride = gridDim.x * blockDim.x;
    for (; i < E; i += stride) {
        int d = dst[i];
        int pos = atomicAdd(&cursor[d], 1);
        edge_pk[pos] = make_int2(src[i], __float_as_int(w[i]));
    }
}

// ---------------- fused CSR gather (bf16) + update, one wave per row -------
// Lane layout: g = lane>>3 (edge slot 0..7), c = lane&7 (channel octet).
// MODE 0: ctx=sum w*seed[s]; num=sum (w*sg)*seed[s]; den; base quality -> bq;
//         fused step-0 update -> poutH (bf16).
// MODE 1: num = sum (w*sg[s])*x[s]; fused update -> poutH.
// MODE 2: ctx = sum w*x[s]; quality + accept vs bq + blend with seedF -> outF.

template <int MODE>
__global__ __launch_bounds__(256) void k_csr(
    const int2* __restrict__ edge_pk, const int* __restrict__ row_start,
    const ushortT* __restrict__ xH, const float* __restrict__ sg,
    const float* __restrict__ seedF, const float* __restrict__ sf,
    const float* __restrict__ conf, const float* __restrict__ gp,
    const float* __restrict__ scal, float* __restrict__ den,
    float* __restrict__ bq, ushortT* __restrict__ poutH,
    float* __restrict__ outF) {
    int lane = threadIdx.x & 63;
    int row = blockIdx.x * 4 + (threadIdx.x >> 6);
    if (row >= NN) return;
    int g = lane >> 3, c = lane & 7;
    int rs = row_start[row], re = row_start[row + 1];

    float acc[8], accn[8];
    float accden = 0.f;
#pragma unroll
    for (int i = 0; i < 8; ++i) { acc[i] = 0.f; accn[i] = 0.f; }

    for (int base = rs; base < re; base += 16) {
        int e0 = base + g;
        int e1 = base + 8 + g;
        int2 pk0 = make_int2(0, 0), pk1 = make_int2(0, 0);
        if (e0 < re) pk0 = edge_pk[e0];
        if (e1 < re) pk1 = edge_pk[e1];
        float w0 = __int_as_float(pk0.y);
        float w1 = __int_as_float(pk1.y);
        const uint4 v0 = *(const uint4*)(xH + (size_t)pk0.x * CC + c * 8);
        const uint4 v1 = *(const uint4*)(xH + (size_t)pk1.x * CC + c * 8);
        float x0[8], x1[8];
        unpack8(v0, x0);
        unpack8(v1, x1);
        float wa0 = w0, wa1 = w1;
        if (MODE == 1) { wa0 = w0 * sg[pk0.x]; wa1 = w1 * sg[pk1.x]; }
#pragma unroll
        for (int i = 0; i < 8; ++i) acc[i] += wa0 * x0[i] + wa1 * x1[i];
        if (MODE == 0) {
            float ws0 = w0 * sg[pk0.x];
            float ws1 = w1 * sg[pk1.x];
#pragma unroll
            for (int i = 0; i < 8; ++i) accn[i] += ws0 * x0[i] + ws1 * x1[i];
            accden += ws0 + ws1;
        }
    }

#pragma unroll
    for (int i = 0; i < 8; ++i) acc[i] = redGSum(acc[i]);

    if (MODE == 1) {
        float dn = fmaxf(den[row], EPSF);
        float inv = 1.f / dn;
        float p[8], s[8], g8[8], f[8];
        uint4 pv = *(const uint4*)(xH + (size_t)row * CC + c * 8);
        unpack8(pv, p);
        const float4 sa = *(const float4*)(seedF + (size_t)row * CC + c * 8);
        const float4 sb = *(const float4*)(seedF + (size_t)row * CC + c * 8 + 4);
        s[0] = sa.x; s[1] = sa.y; s[2] = sa.z; s[3] = sa.w;
        s[4] = sb.x; s[5] = sb.y; s[6] = sb.z; s[7] = sb.w;
        const float4 ga = *(const float4*)(gp + c * 8);
        const float4 gb = *(const float4*)(gp + c * 8 + 4);
        g8[0] = ga.x; g8[1] = ga.y; g8[2] = ga.z; g8[3] = ga.w;
        g8[4] = gb.x; g8[5] = gb.y; g8[6] = gb.z; g8[7] = gb.w;
        float pf = 0.f, pp = 0.f, ff = 0.f, sfv = 0.f, ss = 0.f;
#pragma unroll
        for (int i = 0; i < 8; ++i) {
            f[i] = 0.95f * (acc[i] * inv) + 0.05f * g8[i];
            pf += p[i] * f[i]; pp += p[i] * p[i]; ff += f[i] * f[i];
            sfv += s[i] * f[i]; ss += s[i] * s[i];
        }
        pf = redCSum(pf); pp = redCSum(pp); ff = redCSum(ff);
        sfv = redCSum(sfv); ss = redCSum(ss);
        float nf = fmaxf(sqrtf(ff), 1e-8f);
        float agree = clip01((pf / (fmaxf(sqrtf(pp), 1e-8f) * nf) + 1.f) * 0.5f);
        float sagree = clip01((sfv / (fmaxf(sqrtf(ss), 1e-8f) * nf) + 1.f) * 0.5f);
        float cf = conf[row];
        float anchor = fminf(fmaxf(0.6f + 0.2f * cf, 0.f), 0.995f);
        float lowdeg = clip01(1.f - sf[row * 2 + 0]);
        float lowcl = clip01(1.f - sf[row * 2 + 1]);
        float rec = sigmoidf(8.f * (0.5f - cf));
        float sel = clip01((1.f - cf) + 0.25f * lowdeg + 0.2f * sagree + 0.2f * lowcl);
        float ug = rec * sel * agree * (1.f - anchor);
        float rsc = 0.15f * scal[3] * ug;
        if (g == 0) {
            float o[8];
#pragma unroll
            for (int i = 0; i < 8; ++i)
                o[i] = fmaxf(anchor * s[i] + (1.f - anchor) * p[i] + rsc * (f[i] - p[i]), 0.f);
            *(uint4*)(poutH + (size_t)row * CC + c * 8) = pack8(o);
        }
        return;
    }

    // MODE 0 / MODE 2: quality epilogue. s = seed row (fp32) or prop row (bf16).
    float s[8];
    if (MODE == 0) {
        const float4 sa = *(const float4*)(seedF + (size_t)row * CC + c * 8);
        const float4 sb = *(const float4*)(seedF + (size_t)row * CC + c * 8 + 4);
        s[0] = sa.x; s[1] = sa.y; s[2] = sa.z; s[3] = sa.w;
        s[4] = sb.x; s[5] = sb.y; s[6] = sb.z; s[7] = sb.w;
    } else {
        uint4 pv = *(const uint4*)(xH + (size_t)row * CC + c * 8);
        unpack8(pv, s);
    }
    float dot = 0.f, ss = 0.f, cc2 = 0.f, m = 0.f;
#pragma unroll
    for (int i = 0; i < 8; ++i) {
        dot += s[i] * acc[i]; ss += s[i] * s[i]; cc2 += acc[i] * acc[i]; m += s[i];
    }
    dot = redCSum(dot); ss = redCSum(ss); cc2 = redCSum(cc2); m = redCSum(m);
    float cosv = dot / (fmaxf(sqrtf(ss), 1e-8f) * fmaxf(sqrtf(cc2), 1e-8f));
    float lq = clip01((cosv + 1.f) * 0.5f);
    float minv = 1.f / (m + EPSF);
    float lmax = -3.4e38f;
#pragma unroll
    for (int i = 0; i < 8; ++i) lmax = fmaxf(lmax, s[i] * minv);
    float m1 = redCMax(lmax);
    float cnt = 0.f, mlt = -3.4e38f;
#pragma unroll
    for (int i = 0; i < 8; ++i) {
        float p = s[i] * minv;
        cnt += (p == m1) ? 1.f : 0.f;
        mlt = fmaxf(mlt, (p < m1) ? p : -3.4e38f);
    }
    cnt = redCSum(cnt);
    mlt = redCMax(mlt);
    float m2 = (cnt >= 2.f) ? m1 : mlt;
    float q = 0.7f * lq + 0.2f * (m1 - m2) + 0.1f * sf[row * 2 + 1];

    if (MODE == 0) {
#pragma unroll
        for (int i = 0; i < 8; ++i) accn[i] = redGSum(accn[i]);
        accden = redGSum(accden);
        float dn = fmaxf(accden, EPSF);
        float inv = 1.f / dn;
        float g8[8], f[8];
        const float4 ga = *(const float4*)(gp + c * 8);
        const float4 gb = *(const float4*)(gp + c * 8 + 4);
        g8[0] = ga.x; g8[1] = ga.y; g8[2] = ga.z; g8[3] = ga.w;
        g8[4] = gb.x; g8[5] = gb.y; g8[6] = gb.z; g8[7] = gb.w;
        float sfv = 0.f, ff = 0.f;
#pragma unroll
        for (int i = 0; i < 8; ++i) {
            f[i] = 0.95f * (accn[i] * inv) + 0.05f * g8[i];
            sfv += s[i] * f[i]; ff += f[i] * f[i];
        }
        sfv = redCSum(sfv); ff = redCSum(ff);
        float nf = fmaxf(sqrtf(ff), 1e-8f);
        float sagree = clip01((sfv / (fmaxf(sqrtf(ss), 1e-8f) * nf) + 1.f) * 0.5f);
        float cf = conf[row];
        float anchor = fminf(fmaxf(0.6f + 0.2f * cf, 0.f), 0.995f);
        float lowdeg = clip01(1.f - sf[row * 2 + 0]);
        float lowcl = clip01(1.f - sf[row * 2 + 1]);
        float rec = sigmoidf(8.f * (0.5f - cf));
        float sel = clip01((1.f - cf) + 0.25f * lowdeg + 0.2f * sagree + 0.2f * lowcl);
        float ug = rec * sel * sagree * (1.f - anchor);
        float rsc = 0.15f * scal[3] * ug;
        if (g == 0) {
            float o[8];
#pragma unroll
            for (int i = 0; i < 8; ++i) o[i] = fmaxf(s[i] + rsc * (f[i] - s[i]), 0.f);
            *(uint4*)(poutH + (size_t)row * CC + c * 8) = pack8(o);
        }
        if (lane == 0) {
            den[row] = accden;
            bq[row] = q;
        }
    } else {  // MODE 2: accept + blend -> fp32 out
        float accp = sigmoidf(12.f * (q - bq[row]));
        const float4 sa = *(const float4*)(seedF + (size_t)row * CC + c * 8);
        const float4 sb = *(const float4*)(seedF + (size_t)row * CC + c * 8 + 4);
        float sd[8] = {sa.x, sa.y, sa.z, sa.w, sb.x, sb.y, sb.z, sb.w};
        if (g == 0) {
            float4 o1, o2;
            o1.x = accp * s[0] + (1.f - accp) * sd[0];
            o1.y = accp * s[1] + (1.f - accp) * sd[1];
            o1.z = accp * s[2] + (1.f - accp) * sd[2];
            o1.w = accp * s[3] + (1.f - accp) * sd[3];
            o2.x = accp * s[4] + (1.f - accp) * sd[4];
            o2.y = accp * s[5] + (1.f - accp) * sd[5];
            o2.z = accp * s[6] + (1.f - accp) * sd[6];
            o2.w = accp * s[7] + (1.f - accp) * sd[7];
            *(float4*)(outF + (size_t)row * CC + c * 8) = o1;
            *(float4*)(outF + (size_t)row * CC + c * 8 + 4) = o2;
        }
    }
}

// ---------------- launcher ----------------

extern "C" void kernel_launch(void* const* d_in, const int* in_sizes, int n_in,
                              void* d_out, int out_size, void* d_ws, size_t ws_size,
                              hipStream_t stream) {
    const float* logits = (const float*)d_in[0];
    const float* ew = (const float*)d_in[1];
    const float* sf = (const float*)d_in[2];
    const int* esrc = (const int*)d_in[3];
    const int* edst = (const int*)d_in[4];
    float* out = (float*)d_out;
    int E = in_sizes[1];

    float* ws = (float*)d_ws;
    float* seedF = ws;                             // N*C fp32   (25.6 MB)
    ushortT* seedH = (ushortT*)(seedF + NN * CC);  // N*C bf16   (12.8 MB)
    ushortT* propAH = seedH + NN * CC;             // N*C bf16   (12.8 MB)
    int2* edge_pk = (int2*)(propAH + NN * CC);     // E int2     (12.8 MB)
    int2* tmp_pk = edge_pk + E;                    // E int2     (12.8 MB)
    float* fb = (float*)(tmp_pk + E);
    float* massA = fb;                             // N
    float* certA = massA + NN;                     // N
    float* confA = certA + NN;                     // N
    float* sgA = confA + NN;                       // N
    float* denA = sgA + NN;                        // N
    float* bqA = denA + NN;                        // N
    float* scal = bqA + NN;                        // 16
    float* gp = scal + 16;                         // 64
    int* count = (int*)(gp + 64);                  // N
    int* cursor = count + NN;                      // N
    int* row_start = cursor + NN;                  // N+1
    int* bsum = row_start + NN + 1;                // NSB
    int* boff = bsum + NSB;                        // NSB
    int* cnts = boff + NSB;                        // NREG*RBLK
    int* offs = cnts + NREG * RBLK;                // NREG*RBLK
    ushortT* propBH = (ushortT*)d_out;             // dead before final write

    size_t need_bytes = (size_t)((char*)(offs + NREG * RBLK) - (char*)ws);
    bool sort_path = ws_size >= need_bytes;

    hipMemsetAsync(scal, 0, 16 * sizeof(float), stream);
    hipMemsetAsync(count, 0, NN * sizeof(int), stream);

    const int redBlocks = 1024;
    const int rowBlocks = (NN + 3) / 4;
    const int edgeBlocks = 1024;

    k_seed<<<redBlocks, 256, 0, stream>>>(logits, sf, seedF, seedH, massA, certA, scal);
    k_conf<<<redBlocks, 256, 0, stream>>>(seedF, massA, certA, confA, sgA, scal, gp);
    k_finalize<<<1, 64, 0, stream>>>(scal, gp);

    k_count<<<RBLK, 256, 0, stream>>>(edst, count, cnts, E);
    k_bsum<<<NSB, 256, 0, stream>>>(count, bsum);
    k_boff<<<1, 1, 0, stream>>>(bsum, boff, row_start);
    k_scanwrite<<<NSB, 256, 0, stream>>>(count, boff, row_start, cursor);

    if (sort_path) {
        k_rscan<<<1, 1024, 0, stream>>>(cnts, offs);
        k_rbin<<<RBLK, 256, 0, stream>>>(esrc, edst, ew, offs, tmp_pk, E);
        k_runbin<<<NREG, 256, 0, stream>>>(row_start, tmp_pk, edge_pk);
    } else {
        k_scatter<<<edgeBlocks, 256, 0, stream>>>(esrc, edst, ew, cursor, edge_pk, E);
    }

    // base pass: ctx(seed) quality + den + fused step-0 update -> propAH
    k_csr<0><<<rowBlocks, 256, 0, stream>>>(edge_pk, row_start, seedH, sgA, seedF, sf,
                                            confA, gp, scal, denA, bqA, propAH, nullptr);
    // steps 1,2: gather + fused update, ping-pong propAH <-> propBH(d_out)
    k_csr<1><<<rowBlocks, 256, 0, stream>>>(edge_pk, row_start, propAH, sgA, seedF, sf,
                                            confA, gp, scal, denA, bqA, propBH, nullptr);
    k_csr<1><<<rowBlocks, 256, 0, stream>>>(edge_pk, row_start, propBH, sgA, seedF, sf,
                                            confA, gp, scal, denA, bqA, propAH, nullptr);
    // final: ctx(propAH) + quality + accept + blend -> fp32 out (overwrites dead propBH)
    k_csr<2><<<rowBlocks, 256, 0, stream>>>(edge_pk, row_start, propAH, sgA, seedF, sf,
                                            confA, gp, scal, denA, bqA, nullptr, out);
}